// Round 1
// baseline (1931.463 us; speedup 1.0000x reference)
//
#include <hip/hip_runtime.h>
#include <hip/hip_bf16.h>
#include <cstdint>

#define B_ 8
#define LABEL_NC 19
#define H_ 128
#define W_ 128
#define UC 640
#define EPS_ 1e-5f

typedef __attribute__((ext_vector_type(8))) short s8v;    // 8 bf16 (4 VGPR) MFMA frag
typedef __attribute__((ext_vector_type(4))) float f4v;    // MFMA acc
typedef __attribute__((ext_vector_type(4))) int i4v;      // 16B ld/st
typedef unsigned short ushort_t;

__device__ __forceinline__ ushort_t f2b(float f) {
    union { float f; uint32_t u; } a; a.f = f;
    uint32_t u = a.u;
    return (ushort_t)((u + 0x7FFFu + ((u >> 16) & 1u)) >> 16);  // RNE
}

// ---------------- kernel 0: fold blend weights into combined conv weights ----------------
// Wt layout: [tap(9)][co(512)][ci(640)] bf16.  co<256 = scale (gamma), co>=256 = offset (beta).
// ci<128 = actv channels, ci>=128 = style_map channels.
__global__ void __launch_bounds__(256) k_prep(
    const float* __restrict__ w_gamma, const float* __restrict__ w_beta,
    const float* __restrict__ w_sgamma, const float* __restrict__ w_sbeta,
    const float* __restrict__ b_gamma, const float* __restrict__ b_beta,
    const float* __restrict__ b_sgamma, const float* __restrict__ b_sbeta,
    const float* __restrict__ alpha_beta, const float* __restrict__ alpha_gamma,
    ushort_t* __restrict__ Wt, float* __restrict__ bias_s, float* __restrict__ bias_o)
{
    float wb = 1.f / (1.f + __expf(-alpha_beta[0]));
    float wg = 1.f / (1.f + __expf(-alpha_gamma[0]));
    int gid = blockIdx.x * 256 + threadIdx.x;
    if (gid < 256) bias_s[gid] = wg * b_sgamma[gid] + (1.f - wg) * b_gamma[gid];
    else if (gid < 512) bias_o[gid - 256] = wb * b_sbeta[gid - 256] + (1.f - wb) * b_beta[gid - 256];

    const int total = 9 * 512 * 640;
    for (int idx = gid; idx < total; idx += gridDim.x * 256) {
        int tap = idx / (512 * 640);
        int r = idx - tap * (512 * 640);
        int co = r / 640, ci = r - co * 640;
        int kh = tap / 3, kw = tap - kh * 3;
        float v;
        if (co < 256) {
            if (ci < 128) v = (1.f - wg) * w_gamma[((co * 128 + ci) * 3 + kh) * 3 + kw];
            else          v = wg * w_sgamma[((co * 512 + (ci - 128)) * 3 + kh) * 3 + kw];
        } else {
            int c2 = co - 256;
            if (ci < 128) v = (1.f - wb) * w_beta[((c2 * 128 + ci) * 3 + kh) * 3 + kw];
            else          v = wb * w_sbeta[((c2 * 512 + (ci - 128)) * 3 + kh) * 3 + kw];
        }
        Wt[idx] = f2b(v);
    }
}

// ---------------- kernel 1: per-(b,c) instance-norm stats ----------------
__global__ void __launch_bounds__(256) k_stats(const float* __restrict__ x,
                                               float* __restrict__ mean, float* __restrict__ rstd)
{
    int bc = blockIdx.x;  // b*256+c
    const float4* p = (const float4*)(x + (size_t)bc * (H_ * W_));
    float s = 0.f, s2 = 0.f;
    for (int i = threadIdx.x; i < H_ * W_ / 4; i += 256) {
        float4 v = p[i];
        s += v.x + v.y + v.z + v.w;
        s2 += v.x * v.x + v.y * v.y + v.z * v.z + v.w * v.w;
    }
    #pragma unroll
    for (int o = 32; o > 0; o >>= 1) { s += __shfl_xor(s, o); s2 += __shfl_xor(s2, o); }
    __shared__ float red[8];
    int wave = threadIdx.x >> 6, lane = threadIdx.x & 63;
    if (lane == 0) { red[wave] = s; red[wave + 4] = s2; }
    __syncthreads();
    if (threadIdx.x == 0) {
        float ts = red[0] + red[1] + red[2] + red[3];
        float t2 = red[4] + red[5] + red[6] + red[7];
        float m = ts * (1.f / 16384.f);
        float v = t2 * (1.f / 16384.f) - m * m;
        mean[bc] = m;
        rstd[bc] = rsqrtf(v + EPS_);
    }
}

// ---------------- kernel 2: build U[b][h][w][640] bf16 (NHWC) ----------------
// channels 0..127:   relu(conv3x3(segmap, w_shared) + b_shared)
// channels 128..639: style_map = sum_l style[b,l,s] * segmap[b,l,h,w]
__global__ void __launch_bounds__(256) k_buildU(
    const float* __restrict__ segmap, const float* __restrict__ style,
    const float* __restrict__ w_shared, const float* __restrict__ b_shared,
    ushort_t* __restrict__ U)
{
    int bh = blockIdx.x;
    int b = bh >> 7, h = bh & 127;
    __shared__ float seg[3][LABEL_NC][W_];   // rows h-1,h,h+1
    const float* segb = segmap + (size_t)b * (LABEL_NC * H_ * W_);
    for (int idx = threadIdx.x; idx < 3 * LABEL_NC * W_; idx += 256) {
        int w = idx & 127;
        int l = (idx >> 7) % LABEL_NC;
        int rr = idx / (LABEL_NC * W_);
        int hh = h + rr - 1;
        seg[rr][l][w] = (hh >= 0 && hh < H_) ? segb[((size_t)l * H_ + hh) * W_ + w] : 0.f;
    }
    __syncthreads();

    int t = threadIdx.x;
    int w = t & 127;
    int grp = __builtin_amdgcn_readfirstlane(t >> 7);   // 0 or 1, wave-uniform
    ushort_t* Urow = U + (((size_t)(b * H_ + h)) * W_ + w) * UC;

    // part A: actv channels grp*64 .. grp*64+64, batches of 16
    for (int cb = 0; cb < 4; ++cb) {
        int co0 = grp * 64 + cb * 16;
        float acc[16];
        #pragma unroll
        for (int i = 0; i < 16; ++i) acc[i] = b_shared[co0 + i];
        for (int l = 0; l < LABEL_NC; ++l) {
            #pragma unroll
            for (int kh = 0; kh < 3; ++kh) {
                float sm = (w > 0)   ? seg[kh][l][w - 1] : 0.f;
                float s0 = seg[kh][l][w];
                float sp = (w < 127) ? seg[kh][l][w + 1] : 0.f;
                const float* wp = w_shared + ((size_t)co0 * LABEL_NC + l) * 9 + kh * 3;
                #pragma unroll
                for (int i = 0; i < 16; ++i) {
                    const float* wpi = wp + i * (LABEL_NC * 9);
                    acc[i] += sm * wpi[0] + s0 * wpi[1] + sp * wpi[2];
                }
            }
        }
        #pragma unroll
        for (int i = 0; i < 16; ++i)
            Urow[co0 + i] = f2b(acc[i] > 0.f ? acc[i] : 0.f);
    }

    // part B: style_map channels grp*256 .. +256, batches of 16
    float segr[LABEL_NC];
    #pragma unroll
    for (int l = 0; l < LABEL_NC; ++l) segr[l] = seg[1][l][w];
    const float* styb = style + (size_t)b * (LABEL_NC * 512);
    for (int sb = 0; sb < 16; ++sb) {
        int s0 = grp * 256 + sb * 16;
        float acc[16];
        #pragma unroll
        for (int i = 0; i < 16; ++i) acc[i] = 0.f;
        for (int l = 0; l < LABEL_NC; ++l) {
            const float* sp = styb + l * 512 + s0;
            float sl = segr[l];
            #pragma unroll
            for (int i = 0; i < 16; ++i) acc[i] += sl * sp[i];
        }
        #pragma unroll
        for (int i = 0; i < 16; ++i) Urow[128 + s0 + i] = f2b(acc[i]);
    }
}

// ---------------- kernel 3: main implicit-GEMM conv + fused epilogue ----------------
// Block: one image row (b,h) x 128 output channels, computing BOTH scale and offset halves.
// M-tile = full row of 128 pixels => kw-halo is exactly the SAME zero padding.
#define BK 64
#define LSTR 72   // BK + 8 pad: row stride 144 B (16B-aligned, 2-way bank alias = free)

__global__ void __launch_bounds__(256) k_conv(
    const ushort_t* __restrict__ U, const ushort_t* __restrict__ Wt,
    const float* __restrict__ x, const float* __restrict__ mean, const float* __restrict__ rstd,
    const float* __restrict__ bias_s, const float* __restrict__ bias_o,
    float* __restrict__ out)
{
    int row = blockIdx.x >> 1;
    int cohalf = blockIdx.x & 1;
    int b = row >> 7, h = row & 127;

    __shared__ alignas(16) ushort_t lA[128 * LSTR];
    __shared__ alignas(16) ushort_t lB[2][128 * LSTR];

    int t = threadIdx.x;
    int wave = t >> 6, lane = t & 63;
    int wm = wave >> 1, wn = wave & 1;

    f4v acc[2][4][4] = {};   // [scale/offset][mi][ni]

    const ushort_t* Ub = U + (size_t)b * (H_ * W_ * UC);

    for (int dh = -1; dh <= 1; ++dh) {
        int hh = h + dh;
        bool hok = (hh >= 0 && hh < H_);
        const ushort_t* Urow = Ub + (size_t)hh * (W_ * UC);
        for (int ci0 = 0; ci0 < UC; ci0 += BK) {
            for (int dw = -1; dw <= 1; ++dw) {
                __syncthreads();
                if (dw == -1) {                 // stage A once per (dh, ci0)
                    int aw = t >> 1;
                    int ac = (t & 1) * 32;
                    ushort_t* dst = &lA[aw * LSTR + ac];
                    if (hok) {
                        const ushort_t* src = Urow + (size_t)aw * UC + ci0 + ac;
                        #pragma unroll
                        for (int j = 0; j < 4; ++j)
                            *(i4v*)(dst + j * 8) = *(const i4v*)(src + j * 8);
                    } else {
                        i4v z = {};
                        #pragma unroll
                        for (int j = 0; j < 4; ++j) *(i4v*)(dst + j * 8) = z;
                    }
                }
                {   // stage B (both halves) for tap (dh,dw)
                    int tap = (dh + 1) * 3 + (dw + 1);
                    int half = t >> 7;
                    int col = t & 127;
                    int co = cohalf * 128 + half * 256 + col;
                    const ushort_t* src = Wt + ((size_t)tap * 512 + co) * UC + ci0;
                    ushort_t* dst = &lB[half][col * LSTR];
                    #pragma unroll
                    for (int j = 0; j < 8; ++j)
                        *(i4v*)(dst + j * 8) = *(const i4v*)(src + j * 8);
                }
                __syncthreads();
                #pragma unroll
                for (int ks = 0; ks < 2; ++ks) {
                    int kb = ks * 32 + (lane >> 4) * 8;
                    s8v af[4];
                    #pragma unroll
                    for (int mi = 0; mi < 4; ++mi) {
                        int p = wm * 64 + mi * 16 + (lane & 15);
                        int q = p + dw;
                        int qc = q < 0 ? 0 : (q > 127 ? 127 : q);
                        s8v v = *(const s8v*)&lA[qc * LSTR + kb];
                        if (q < 0 || q > 127) { s8v z = {}; v = z; }
                        af[mi] = v;
                    }
                    s8v bfr[2][4];
                    #pragma unroll
                    for (int hf = 0; hf < 2; ++hf)
                        #pragma unroll
                        for (int ni = 0; ni < 4; ++ni) {
                            int c = wn * 64 + ni * 16 + (lane & 15);
                            bfr[hf][ni] = *(const s8v*)&lB[hf][c * LSTR + kb];
                        }
                    #pragma unroll
                    for (int hf = 0; hf < 2; ++hf)
                        #pragma unroll
                        for (int mi = 0; mi < 4; ++mi)
                            #pragma unroll
                            for (int ni = 0; ni < 4; ++ni)
                                acc[hf][mi][ni] = __builtin_amdgcn_mfma_f32_16x16x32_bf16(
                                    af[mi], bfr[hf][ni], acc[hf][mi][ni], 0, 0, 0);
                }
            }
        }
    }

    // fused epilogue: out = (x - mu) * rstd * (scale_acc + bias_s + 1) + (offset_acc + bias_o)
    int bc_base = b * 256;
    #pragma unroll
    for (int ni = 0; ni < 4; ++ni) {
        int c = cohalf * 128 + wn * 64 + ni * 16 + (lane & 15);
        float bs = bias_s[c] + 1.f;
        float bo = bias_o[c];
        float mu = mean[bc_base + c];
        float rs = rstd[bc_base + c];
        #pragma unroll
        for (int mi = 0; mi < 4; ++mi) {
            #pragma unroll
            for (int r = 0; r < 4; ++r) {
                int p = wm * 64 + mi * 16 + (lane >> 4) * 4 + r;
                size_t xi = (((size_t)(bc_base + c)) * H_ + h) * W_ + p;
                float xn = (x[xi] - mu) * rs;
                out[xi] = xn * (acc[0][mi][ni][r] + bs) + (acc[1][mi][ni][r] + bo);
            }
        }
    }
}

// ---------------- launcher ----------------
extern "C" void kernel_launch(void* const* d_in, const int* in_sizes, int n_in,
                              void* d_out, int out_size, void* d_ws, size_t ws_size,
                              hipStream_t stream)
{
    const float* x        = (const float*)d_in[0];
    const float* segmap   = (const float*)d_in[1];
    const float* style    = (const float*)d_in[2];
    const float* w_shared = (const float*)d_in[3];
    const float* b_shared = (const float*)d_in[4];
    const float* w_gamma  = (const float*)d_in[5];
    const float* b_gamma  = (const float*)d_in[6];
    const float* w_beta   = (const float*)d_in[7];
    const float* b_beta   = (const float*)d_in[8];
    const float* w_sgamma = (const float*)d_in[9];
    const float* b_sgamma = (const float*)d_in[10];
    const float* w_sbeta  = (const float*)d_in[11];
    const float* b_sbeta  = (const float*)d_in[12];
    const float* alpha_beta  = (const float*)d_in[13];
    const float* alpha_gamma = (const float*)d_in[14];
    float* out = (float*)d_out;

    char* ws = (char*)d_ws;
    float*    ws_mean  = (float*)(ws + 0);            // 2048 f32
    float*    ws_rstd  = (float*)(ws + 8192);         // 2048 f32
    float*    ws_bs    = (float*)(ws + 16384);        // 256 f32
    float*    ws_bo    = (float*)(ws + 18432);        // 256 f32
    ushort_t* ws_Wt    = (ushort_t*)(ws + 20480);     // 9*512*640 bf16 = 5.9 MB
    ushort_t* ws_U     = (ushort_t*)(ws + 6 * 1024 * 1024);  // 8*128*128*640 bf16 = 167.8 MB

    k_prep<<<dim3(2048), dim3(256), 0, stream>>>(w_gamma, w_beta, w_sgamma, w_sbeta,
                                                 b_gamma, b_beta, b_sgamma, b_sbeta,
                                                 alpha_beta, alpha_gamma, ws_Wt, ws_bs, ws_bo);
    k_stats<<<dim3(2048), dim3(256), 0, stream>>>(x, ws_mean, ws_rstd);
    k_buildU<<<dim3(1024), dim3(256), 0, stream>>>(segmap, style, w_shared, b_shared, ws_U);
    k_conv<<<dim3(2048), dim3(256), 0, stream>>>(ws_U, ws_Wt, x, ws_mean, ws_rstd,
                                                 ws_bs, ws_bo, out);
}

// Round 3
// 966.329 us; speedup vs baseline: 1.9988x; 1.9988x over previous
//
#include <hip/hip_runtime.h>
#include <hip/hip_bf16.h>
#include <cstdint>

#define B_ 8
#define LABEL_NC 19
#define H_ 128
#define W_ 128
#define UC 640
#define EPS_ 1e-5f

typedef __attribute__((ext_vector_type(8))) short s8v;    // 8 bf16 (4 VGPR) MFMA frag
typedef __attribute__((ext_vector_type(4))) float f4v;    // MFMA acc
typedef __attribute__((ext_vector_type(4))) int i4v;      // 16B ld/st
typedef unsigned short ushort_t;

__device__ __forceinline__ ushort_t f2b(float f) {
    union { float f; uint32_t u; } a; a.f = f;
    uint32_t u = a.u;
    return (ushort_t)((u + 0x7FFFu + ((u >> 16) & 1u)) >> 16);  // RNE
}

__device__ __forceinline__ void gl2lds16(const ushort_t* g, ushort_t* l) {
    __builtin_amdgcn_global_load_lds(
        (const __attribute__((address_space(1))) unsigned int*)g,
        (__attribute__((address_space(3))) unsigned int*)l, 16, 0, 0);
}

// ---------------- kernel 0: fold blend weights into combined conv weights ----------------
// Wt layout: [tap(9)][co(512)][ci(640)] bf16.  co<256 = scale (gamma), co>=256 = offset (beta).
__global__ void __launch_bounds__(256) k_prep(
    const float* __restrict__ w_gamma, const float* __restrict__ w_beta,
    const float* __restrict__ w_sgamma, const float* __restrict__ w_sbeta,
    const float* __restrict__ b_gamma, const float* __restrict__ b_beta,
    const float* __restrict__ b_sgamma, const float* __restrict__ b_sbeta,
    const float* __restrict__ alpha_beta, const float* __restrict__ alpha_gamma,
    ushort_t* __restrict__ Wt, float* __restrict__ bias_s, float* __restrict__ bias_o)
{
    float wb = 1.f / (1.f + __expf(-alpha_beta[0]));
    float wg = 1.f / (1.f + __expf(-alpha_gamma[0]));
    int gid = blockIdx.x * 256 + threadIdx.x;
    if (gid < 256) bias_s[gid] = wg * b_sgamma[gid] + (1.f - wg) * b_gamma[gid];
    else if (gid < 512) bias_o[gid - 256] = wb * b_sbeta[gid - 256] + (1.f - wb) * b_beta[gid - 256];

    const int total = 9 * 512 * 640;
    for (int idx = gid; idx < total; idx += gridDim.x * 256) {
        int tap = idx / (512 * 640);
        int r = idx - tap * (512 * 640);
        int co = r / 640, ci = r - co * 640;
        int kh = tap / 3, kw = tap - kh * 3;
        float v;
        if (co < 256) {
            if (ci < 128) v = (1.f - wg) * w_gamma[((co * 128 + ci) * 3 + kh) * 3 + kw];
            else          v = wg * w_sgamma[((co * 512 + (ci - 128)) * 3 + kh) * 3 + kw];
        } else {
            int c2 = co - 256;
            if (ci < 128) v = (1.f - wb) * w_beta[((c2 * 128 + ci) * 3 + kh) * 3 + kw];
            else          v = wb * w_sbeta[((c2 * 512 + (ci - 128)) * 3 + kh) * 3 + kw];
        }
        Wt[idx] = f2b(v);
    }
}

// ---------------- kernel 1: per-(b,c) instance-norm stats ----------------
__global__ void __launch_bounds__(256) k_stats(const float* __restrict__ x,
                                               float* __restrict__ mean, float* __restrict__ rstd)
{
    int bc = blockIdx.x;  // b*256+c
    const float4* p = (const float4*)(x + (size_t)bc * (H_ * W_));
    float s = 0.f, s2 = 0.f;
    for (int i = threadIdx.x; i < H_ * W_ / 4; i += 256) {
        float4 v = p[i];
        s += v.x + v.y + v.z + v.w;
        s2 += v.x * v.x + v.y * v.y + v.z * v.z + v.w * v.w;
    }
    #pragma unroll
    for (int o = 32; o > 0; o >>= 1) { s += __shfl_xor(s, o); s2 += __shfl_xor(s2, o); }
    __shared__ float red[8];
    int wave = threadIdx.x >> 6, lane = threadIdx.x & 63;
    if (lane == 0) { red[wave] = s; red[wave + 4] = s2; }
    __syncthreads();
    if (threadIdx.x == 0) {
        float ts = red[0] + red[1] + red[2] + red[3];
        float t2 = red[4] + red[5] + red[6] + red[7];
        float m = ts * (1.f / 16384.f);
        float v = t2 * (1.f / 16384.f) - m * m;
        mean[bc] = m;
        rstd[bc] = rsqrtf(v + EPS_);
    }
}

// ---------------- kernel 2: build U[b][h][w][640] bf16 (NHWC) ----------------
__global__ void __launch_bounds__(256) k_buildU(
    const float* __restrict__ segmap, const float* __restrict__ style,
    const float* __restrict__ w_shared, const float* __restrict__ b_shared,
    ushort_t* __restrict__ U)
{
    int bh = blockIdx.x;
    int b = bh >> 7, h = bh & 127;
    __shared__ float seg[3][LABEL_NC][W_];   // rows h-1,h,h+1
    const float* segb = segmap + (size_t)b * (LABEL_NC * H_ * W_);
    for (int idx = threadIdx.x; idx < 3 * LABEL_NC * W_; idx += 256) {
        int w = idx & 127;
        int l = (idx >> 7) % LABEL_NC;
        int rr = idx / (LABEL_NC * W_);
        int hh = h + rr - 1;
        seg[rr][l][w] = (hh >= 0 && hh < H_) ? segb[((size_t)l * H_ + hh) * W_ + w] : 0.f;
    }
    __syncthreads();

    int t = threadIdx.x;
    int w = t & 127;
    int grp = __builtin_amdgcn_readfirstlane(t >> 7);   // 0 or 1, wave-uniform
    ushort_t* Urow = U + (((size_t)(b * H_ + h)) * W_ + w) * UC;

    for (int cb = 0; cb < 4; ++cb) {
        int co0 = grp * 64 + cb * 16;
        float acc[16];
        #pragma unroll
        for (int i = 0; i < 16; ++i) acc[i] = b_shared[co0 + i];
        for (int l = 0; l < LABEL_NC; ++l) {
            #pragma unroll
            for (int kh = 0; kh < 3; ++kh) {
                float sm = (w > 0)   ? seg[kh][l][w - 1] : 0.f;
                float s0 = seg[kh][l][w];
                float sp = (w < 127) ? seg[kh][l][w + 1] : 0.f;
                const float* wp = w_shared + ((size_t)co0 * LABEL_NC + l) * 9 + kh * 3;
                #pragma unroll
                for (int i = 0; i < 16; ++i) {
                    const float* wpi = wp + i * (LABEL_NC * 9);
                    acc[i] += sm * wpi[0] + s0 * wpi[1] + sp * wpi[2];
                }
            }
        }
        #pragma unroll
        for (int i = 0; i < 16; ++i)
            Urow[co0 + i] = f2b(acc[i] > 0.f ? acc[i] : 0.f);
    }

    float segr[LABEL_NC];
    #pragma unroll
    for (int l = 0; l < LABEL_NC; ++l) segr[l] = seg[1][l][w];
    const float* styb = style + (size_t)b * (LABEL_NC * 512);
    for (int sb = 0; sb < 16; ++sb) {
        int s0 = grp * 256 + sb * 16;
        float acc[16];
        #pragma unroll
        for (int i = 0; i < 16; ++i) acc[i] = 0.f;
        for (int l = 0; l < LABEL_NC; ++l) {
            const float* sp = styb + l * 512 + s0;
            float sl = segr[l];
            #pragma unroll
            for (int i = 0; i < 16; ++i) acc[i] += sl * sp[i];
        }
        #pragma unroll
        for (int i = 0; i < 16; ++i) Urow[128 + s0 + i] = f2b(acc[i]);
    }
}

// ---------------- kernel 3: main implicit-GEMM conv + fused epilogue ----------------
// 512 threads (8 waves, 4wm x 2wn). M-tile = 256 pixels (2 rows), N = 256 (128 scale + 128
// offset channels, interleaved so each wave holds scale/offset pairs). 2-phase pipeline:
// A (4 U-rows x BK=64, XOR-swizzled, 64KB) staged once per ci-chunk via global_load_lds;
// B (256x64, 32KB) double-buffered, prefetched before compute. K = 10 ci-chunks x 9 taps.
#define BK 64

__global__ void __launch_bounds__(512, 1) k_conv(
    const ushort_t* __restrict__ U, const ushort_t* __restrict__ Wt,
    const float* __restrict__ x, const float* __restrict__ mean, const float* __restrict__ rstd,
    const float* __restrict__ bias_s, const float* __restrict__ bias_o,
    float* __restrict__ out)
{
    // bijective XCD-chunk swizzle (nwg=1024, 128 per XCD)
    int orig = blockIdx.x;
    int wg = (orig & 7) * 128 + (orig >> 3);
    int mtile = wg >> 1;
    int cohalf = wg & 1;
    int b = mtile >> 6;
    int h0 = (mtile & 63) << 1;

    extern __shared__ ushort_t smem[];
    ushort_t* sA = smem;                 // 4*128*64 = 32768 ushorts (64KB)
    // sB buffers live at smem + 32768 + bi*16384 (2 x 32KB)

    int t = threadIdx.x;
    int wv = t >> 6, ln = t & 63;
    int wm = wv >> 1, wn = wv & 1;

    const ushort_t* Ub = U + (size_t)b * (H_ * W_ * UC);

    f4v acc[4][8] = {};   // [mi][ni]; ni<4 scale, ni>=4 offset (same channels)

    // ---- staging helpers ----
    auto stage_A = [&](int ci0) {
        #pragma unroll
        for (int i = 0; i < 8; ++i) {
            int issue = wv * 8 + i;          // 64 issues of 1KB
            int r = issue >> 4;              // wave-uniform LDS row group
            int hh = h0 - 1 + r;
            ushort_t* dst = sA + (size_t)issue * 512;
            if (hh >= 0 && hh < H_) {
                int u = issue * 64 + ln;
                int w = (u >> 3) & 127;
                int sl = u & 7;
                const ushort_t* src = Ub + ((size_t)hh * W_ + w) * UC + ci0 + ((sl ^ (w & 7)) << 3);
                gl2lds16(src, dst);
            } else {
                i4v z = {};
                *(i4v*)(sA + (size_t)(issue * 64 + ln) * 8) = z;
            }
        }
    };
    auto stage_B = [&](int tap, int ci0, int bi) {
        ushort_t* base = smem + 32768 + (size_t)bi * 16384;
        #pragma unroll
        for (int j = 0; j < 4; ++j) {
            int issue = wv * 4 + j;          // 32 issues of 1KB
            int c = issue * 8 + (ln >> 3);   // LDS row (0..255)
            int sl = ln & 7;
            int g = (c >> 6) & 1;
            int cbase = ((c >> 7) << 6) + (c & 63);
            int co = g * 256 + cohalf * 128 + cbase;
            const ushort_t* src = Wt + ((size_t)tap * 512 + co) * UC + ci0 + ((sl ^ (c & 7)) << 3);
            gl2lds16(src, base + (size_t)issue * 512);
        }
    };

    // ---- prologue ----
    stage_A(0);
    stage_B(0, 0, 0);
    __syncthreads();

    int buf = 0;
    for (int ch = 0; ch < 10; ++ch) {
        int ci0 = ch * 64;
        for (int tap = 0; tap < 9; ++tap) {
            int dhp1 = tap / 3;           // dh+1 in [0,2]
            int dw = tap - dhp1 * 3 - 1;  // [-1,1]
            if (tap < 8) stage_B(tap + 1, ci0, buf ^ 1);

            // ---- compute tap from sA (rows dhp1..dhp1+1) and sB[buf] ----
            ushort_t* sBb = smem + 32768 + (size_t)buf * 16384;
            #pragma unroll
            for (int ks = 0; ks < 2; ++ks) {
                int sd = ks * 4 + (ln >> 4);   // data slot (16B unit within 128B row)
                s8v af[4];
                #pragma unroll
                for (int mi = 0; mi < 4; ++mi) {
                    int p = wm * 64 + mi * 16 + (ln & 15);
                    int r = (p >> 7) + dhp1;
                    int q = (p & 127) + dw;
                    int qc = q < 0 ? 0 : (q > 127 ? 127 : q);
                    s8v v = *(const s8v*)&sA[(size_t)(((r * 128 + qc) * 8) + (sd ^ (qc & 7))) * 8];
                    if (q < 0 || q > 127) { s8v z = {}; v = z; }
                    af[mi] = v;
                }
                s8v bf[8];
                #pragma unroll
                for (int ni = 0; ni < 8; ++ni) {
                    int c = wn * 128 + (ni >> 2) * 64 + (ni & 3) * 16 + (ln & 15);
                    bf[ni] = *(const s8v*)&sBb[(size_t)((c * 8) + (sd ^ (c & 7))) * 8];
                }
                #pragma unroll
                for (int mi = 0; mi < 4; ++mi)
                    #pragma unroll
                    for (int ni = 0; ni < 8; ++ni)
                        acc[mi][ni] = __builtin_amdgcn_mfma_f32_16x16x32_bf16(
                            af[mi], bf[ni], acc[mi][ni], 0, 0, 0);
            }

            __syncthreads();
            if (tap == 8 && ch < 9) {
                stage_A(ci0 + 64);
                stage_B(0, ci0 + 64, buf ^ 1);
                __syncthreads();
            }
            buf ^= 1;
        }
    }

    // ---- fused epilogue: out = (x-mu)*rstd*(scale+bs+1) + (offset+bo) ----
    int bc_base = b * 256;
    #pragma unroll
    for (int ni = 0; ni < 4; ++ni) {
        int chn = cohalf * 128 + wn * 64 + ni * 16 + (ln & 15);
        float bs = bias_s[chn] + 1.f;
        float bo = bias_o[chn];
        float mu = mean[bc_base + chn];
        float rs = rstd[bc_base + chn];
        #pragma unroll
        for (int mi = 0; mi < 4; ++mi) {
            #pragma unroll
            for (int r = 0; r < 4; ++r) {
                int p = wm * 64 + mi * 16 + ((ln >> 4) << 2) + r;
                int hh = h0 + (p >> 7);
                int ww = p & 127;
                size_t xi = (((size_t)(bc_base + chn)) * H_ + hh) * W_ + ww;
                float xn = (x[xi] - mu) * rs;
                out[xi] = xn * (acc[mi][ni][r] + bs) + (acc[mi][ni + 4][r] + bo);
            }
        }
    }
}

// ---------------- launcher ----------------
extern "C" void kernel_launch(void* const* d_in, const int* in_sizes, int n_in,
                              void* d_out, int out_size, void* d_ws, size_t ws_size,
                              hipStream_t stream)
{
    const float* x        = (const float*)d_in[0];
    const float* segmap   = (const float*)d_in[1];
    const float* style    = (const float*)d_in[2];
    const float* w_shared = (const float*)d_in[3];
    const float* b_shared = (const float*)d_in[4];
    const float* w_gamma  = (const float*)d_in[5];
    const float* b_gamma  = (const float*)d_in[6];
    const float* w_beta   = (const float*)d_in[7];
    const float* b_beta   = (const float*)d_in[8];
    const float* w_sgamma = (const float*)d_in[9];
    const float* b_sgamma = (const float*)d_in[10];
    const float* w_sbeta  = (const float*)d_in[11];
    const float* b_sbeta  = (const float*)d_in[12];
    const float* alpha_beta  = (const float*)d_in[13];
    const float* alpha_gamma = (const float*)d_in[14];
    float* out = (float*)d_out;

    char* ws = (char*)d_ws;
    float*    ws_mean  = (float*)(ws + 0);            // 2048 f32
    float*    ws_rstd  = (float*)(ws + 8192);         // 2048 f32
    float*    ws_bs    = (float*)(ws + 16384);        // 256 f32
    float*    ws_bo    = (float*)(ws + 18432);        // 256 f32
    ushort_t* ws_Wt    = (ushort_t*)(ws + 20480);     // 9*512*640 bf16 = 5.9 MB
    ushort_t* ws_U     = (ushort_t*)(ws + 6 * 1024 * 1024);  // 8*128*128*640 bf16 = 167.8 MB

    (void)hipFuncSetAttribute((const void*)k_conv,
                              hipFuncAttributeMaxDynamicSharedMemorySize, 131072);

    k_prep<<<dim3(2048), dim3(256), 0, stream>>>(w_gamma, w_beta, w_sgamma, w_sbeta,
                                                 b_gamma, b_beta, b_sgamma, b_sbeta,
                                                 alpha_beta, alpha_gamma, ws_Wt, ws_bs, ws_bo);
    k_stats<<<dim3(2048), dim3(256), 0, stream>>>(x, ws_mean, ws_rstd);
    k_buildU<<<dim3(1024), dim3(256), 0, stream>>>(segmap, style, w_shared, b_shared, ws_U);
    k_conv<<<dim3(1024), dim3(512), 131072, stream>>>(ws_U, ws_Wt, x, ws_mean, ws_rstd,
                                                      ws_bs, ws_bo, out);
}